// Round 18
// baseline (616.375 us; speedup 1.0000x reference)
//
#include <hip/hip_runtime.h>
#include <stdint.h>

// CapsuleNet forward on MI355X — round 18.
// Single change vs r17: conv1 split spatially 2x — each block computes 10
// output rows (half = bid&1) of one batch, loading 18 input rows (504 f32)
// to LDS. Grid 1024 conv1 blocks -> 4 blocks/CU (was 2): doubles waves/SIMD
// for the VALU-bound conv1. Per-output FMA body/order identical -> hT
// bitwise identical -> output bitwise identical (absmax 6.103516e-05).
// conv2 (r17: 240us, 16-wave retile) and everything else frozen.
//
// ws layout (total ~134.8 MB):
//   hT  fp16 [512][20][20][256]   @0           104,857,600
//   A2  fp16 [256][20736]         @104,857,600  10,616,832
//   u   f32  [512][9216]          @115,474,432  18,874,368  (squashed in place)
//   bij f32  [1152][10]           @134,348,800      46,080
//   cT  f32  [10][1152]           @134,394,880      46,080
//   s   f32  [160][512]           @134,440,960     327,680
//  aliased over dead hT after conv2:
//   ub  fp16 [512][9216]          @0             9,437,184
//   ubT fp16 [9216][512]          @9,437,184     9,437,184
//   vb  fp16 [160][512]           @21,823,488      163,840

typedef unsigned short u16;
typedef unsigned int u32;
typedef _Float16 half8 __attribute__((ext_vector_type(8)));
typedef float f32x4 __attribute__((ext_vector_type(4)));

__device__ __forceinline__ u16 f2h(float f) {
  union { _Float16 h; u16 u; } cv;
  cv.h = (_Float16)f;
  return cv.u;
}

__device__ __forceinline__ void gload_lds16(const void* g, void* l) {
  __builtin_amdgcn_global_load_lds(
      (const __attribute__((address_space(1))) void*)g,
      (__attribute__((address_space(3))) void*)l, 16, 0, 0);
}

// ---------------- prologue: conv1 (bid<1024) | prep_w2 (1024..1279) | init_u ----------------
__global__ __launch_bounds__(256) void prologue_kernel(
    const float* __restrict__ x, const float* __restrict__ w1,
    const float* __restrict__ b1, const float* __restrict__ w2,
    const float* __restrict__ b2, u16* __restrict__ hT,
    u16* __restrict__ A2, float* __restrict__ u) {
  __shared__ __align__(16) char smraw[81 * 264 * 2];  // union: xs (2KB) / tl (42.8KB)
  int bid = blockIdx.x;
  int tid = threadIdx.x;
  if (bid < 1024) {
    // ---- conv1: lane=co, 10 output rows per block (half split), x rows in LDS ----
    float* xs = (float*)smraw;  // 18 input rows = 504 floats
    int b = bid >> 1, half = bid & 1;
    int co = tid;
    const float* xbase = x + (size_t)b * 784 + half * 280;  // row half*10
    for (int i = co; i < 504; i += 256) xs[i] = xbase[i];
    float w[81];
    const float* wp = w1 + co * 81;
#pragma unroll
    for (int k = 0; k < 81; ++k) w[k] = wp[k];
    float bias = b1[co];
    __syncthreads();
    u16* hb = hT + (size_t)b * 102400 + co;
    for (int yp = 0; yp < 5; ++yp) {
      int y0l = yp * 2;                 // local row in xs
      int y0g = half * 10 + y0l;        // global output row
      for (int g = 0; g < 5; ++g) {
        int xo = g * 4;
        float a0[4], a1[4];
#pragma unroll
        for (int j = 0; j < 4; ++j) { a0[j] = bias; a1[j] = bias; }
#pragma unroll
        for (int ky2 = 0; ky2 < 10; ++ky2) {
          const float* row = &xs[(y0l + ky2) * 28 + xo];
          float4 r0 = *(const float4*)row;
          float4 r1 = *(const float4*)(row + 4);
          float4 r2 = *(const float4*)(row + 8);
          float xr[12] = {r0.x, r0.y, r0.z, r0.w, r1.x, r1.y, r1.z, r1.w,
                          r2.x, r2.y, r2.z, r2.w};
          if (ky2 < 9) {
#pragma unroll
            for (int kx = 0; kx < 9; ++kx) {
              float wv = w[ky2 * 9 + kx];
              a0[0] = fmaf(wv, xr[kx], a0[0]);
              a0[1] = fmaf(wv, xr[kx + 1], a0[1]);
              a0[2] = fmaf(wv, xr[kx + 2], a0[2]);
              a0[3] = fmaf(wv, xr[kx + 3], a0[3]);
            }
          }
          if (ky2 >= 1) {
#pragma unroll
            for (int kx = 0; kx < 9; ++kx) {
              float wv = w[(ky2 - 1) * 9 + kx];
              a1[0] = fmaf(wv, xr[kx], a1[0]);
              a1[1] = fmaf(wv, xr[kx + 1], a1[1]);
              a1[2] = fmaf(wv, xr[kx + 2], a1[2]);
              a1[3] = fmaf(wv, xr[kx + 3], a1[3]);
            }
          }
        }
#pragma unroll
        for (int j = 0; j < 4; ++j) {
          hb[(y0g * 20 + xo + j) * 256] = f2h(fmaxf(a0[j], 0.f));
          hb[((y0g + 1) * 20 + xo + j) * 256] = f2h(fmaxf(a1[j], 0.f));
        }
      }
    }
  } else if (bid < 1280) {
    // ---- prep_w2 ----
    u16* tl = (u16*)smraw;  // pitch 264 u16
    int co = bid - 1024;
    const float* wp = w2 + (size_t)co * 20736;
#pragma unroll
    for (int k = 0; k < 81; ++k) {
      int li = k * 256 + tid;  // li = ci*81 + t
      int ci = li / 81, t = li - ci * 81;
      tl[t * 264 + ci] = f2h(wp[li]);
    }
    __syncthreads();
    u16* op = A2 + (size_t)co * 20736;
    for (int oc = tid; oc < 2592; oc += 256) {
      int k0 = oc * 8;
      int t = k0 >> 8, ci0 = k0 & 255;
      *(uint4*)(op + k0) = *(const uint4*)&tl[t * 264 + ci0];
    }
  } else {
    // ---- init_u ----
    int i = (bid - 1280) * 256 + tid;
    int b = i / 2304, j0 = (i - b * 2304) * 4;
    float4 v;
    v.x = b2[j0 / 36]; v.y = b2[(j0 + 1) / 36];
    v.z = b2[(j0 + 2) / 36]; v.w = b2[(j0 + 3) / 36];
    *(float4*)(u + (size_t)b * 9216 + j0) = v;
  }
}

// ---------------- conv2 implicit GEMM: 256x256, BK=64, 16 waves of 64x64 (r17) ----------------
__global__ __launch_bounds__(1024, 4) void conv2_kernel(
    const u16* __restrict__ hT, const u16* __restrict__ A2,
    float* __restrict__ u) {
  __shared__ __align__(16) u16 lds_[65536];  // 131072 B = 2 bufs x (A 32KB | B 32KB)
  char* const ldsc = (char*)lds_;
  const int bx = blockIdx.x;
  const int nbk = bx % 72, kz = bx / 72;
  const int n0 = nbk * 256;
  const int tid = threadIdx.x;
  const int lane = tid & 63, w = tid >> 6;  // w 0..15
  const int wr = w >> 2, wc = w & 3;        // 4x4 wave grid
  const int fr = lane & 15, fg = lane >> 4;
  const int w1024 = w * 1024;

  const int rA = tid >> 3;                  // 0..127
  const int qs = (tid & 7) ^ (rA & 7);      // source pre-swizzle (rule 21)
  const int Aoff0 = rA * 20736 + qs * 8;
  const int Aoff1 = (128 + rA) * 20736 + qs * 8;
  int Bb0, Bb1;
  {
    int n = n0 + rA;
    int b = n / 36, sp = n - b * 36, oh = sp / 6, ow = sp - oh * 6;
    Bb0 = (b * 400 + oh * 40 + ow * 2) * 256 + qs * 8;
    n = n0 + 128 + rA;
    b = n / 36; sp = n - b * 36; oh = sp / 6; ow = sp - oh * 6;
    Bb1 = (b * 400 + oh * 40 + ow * 2) * 256 + qs * 8;
  }

  const int kx0 = (fg ^ (fr & 7)) << 4;
  const int kx1 = ((4 + fg) ^ (fr & 7)) << 4;
  const int arow = wr * 64 + fr;  // + mr*16
  const int brow = wc * 64 + fr;  // + nr*16

  f32x4 acc[4][4] = {};
  half8 areg[4], breg[4];

#define STAGE4(E, GT) do {                                                   \
    int tap_ = (GT) >> 2;                                                    \
    int kh_ = tap_ / 9, kw_ = tap_ - kh_ * 9;                                \
    int bo_ = (kh_ * 20 + kw_) * 256 + ((GT) & 3) * 64;                      \
    char* base_ = ldsc + (E) * 65536;                                        \
    gload_lds16(A2 + Aoff0 + (GT) * 64, base_ + w1024);                      \
    gload_lds16(A2 + Aoff1 + (GT) * 64, base_ + 16384 + w1024);              \
    gload_lds16(hT + Bb0 + bo_, base_ + 32768 + w1024);                      \
    gload_lds16(hT + Bb1 + bo_, base_ + 49152 + w1024);                      \
  } while (0)
#define RD8(D, KX) do { _Pragma("unroll")                                    \
    for (int mr = 0; mr < 4; ++mr)                                           \
      areg[mr] = *(const half8*)(ldsc + (D) * 65536 +                        \
                                 (arow + mr * 16) * 128 + (KX));             \
    _Pragma("unroll")                                                        \
    for (int nr = 0; nr < 4; ++nr)                                           \
      breg[nr] = *(const half8*)(ldsc + (D) * 65536 + 32768 +                \
                                 (brow + nr * 16) * 128 + (KX));             \
  } while (0)
#define MM16() do {                                                          \
    __builtin_amdgcn_s_setprio(1);                                           \
    _Pragma("unroll") for (int mr = 0; mr < 4; ++mr)                         \
    _Pragma("unroll") for (int nr = 0; nr < 4; ++nr)                         \
      acc[mr][nr] = __builtin_amdgcn_mfma_f32_16x16x32_f16(                  \
          areg[mr], breg[nr], acc[mr][nr], 0, 0, 0);                         \
    __builtin_amdgcn_s_setprio(0);                                           \
  } while (0)
#define LGKM() do {                                                          \
    asm volatile("s_waitcnt lgkmcnt(0)" ::: "memory");                       \
    __builtin_amdgcn_sched_barrier(0);                                       \
  } while (0)
#define VM_BAR0() do {                                                       \
    asm volatile("s_waitcnt vmcnt(0)" ::: "memory");                         \
    __builtin_amdgcn_s_barrier();                                            \
    asm volatile("" ::: "memory");                                           \
  } while (0)
#define TILE_STD(T, D, E) do {                                               \
    RD8(D, kx0);                                                             \
    STAGE4(E, kz * 108 + (T) + 1);                                           \
    LGKM(); MM16();                                                          \
    RD8(D, kx1); LGKM(); MM16();                                             \
    VM_BAR0();                                                               \
  } while (0)
#define TILE_LAST(D) do {                                                    \
    RD8(D, kx0); LGKM(); MM16();                                             \
    RD8(D, kx1); LGKM(); MM16();                                             \
  } while (0)

  STAGE4(0, kz * 108);
  asm volatile("s_waitcnt vmcnt(0)" ::: "memory");
  __builtin_amdgcn_s_barrier();
  asm volatile("" ::: "memory");

  for (int tt = 0; tt < 53; ++tt) {
    TILE_STD(2 * tt, 0, 1);
    TILE_STD(2 * tt + 1, 1, 0);
  }
  TILE_STD(106, 0, 1);
  TILE_LAST(1);

#pragma unroll
  for (int nf = 0; nf < 4; ++nf) {
    int cn = n0 + wc * 64 + nf * 16 + fr;
    int ob = cn / 36;
    int os = cn - ob * 36;
    float* op = u + (size_t)ob * 9216 + os;
#pragma unroll
    for (int mf = 0; mf < 4; ++mf) {
      int row0 = wr * 64 + mf * 16 + fg * 4;
#pragma unroll
      for (int qq = 0; qq < 4; ++qq)
        atomicAdd(op + (row0 + qq) * 36, acc[mf][nf][qq]);
    }
  }
#undef STAGE4
#undef RD8
#undef MM16
#undef LGKM
#undef VM_BAR0
#undef TILE_STD
#undef TILE_LAST
}

// ---------------- squash: u := squash(u) in place (fp32) + ub fp16 ----------------
__global__ __launch_bounds__(256) void squash_kernel(
    float* __restrict__ u, u16* __restrict__ ub) {
  int idx = blockIdx.x * 256 + threadIdx.x;  // 589,824 = b*1152 + r
  float* up = u + (size_t)idx * 8;
  float4 a = *(const float4*)up;
  float4 c = *(const float4*)(up + 4);
  float sq = a.x * a.x + a.y * a.y + a.z * a.z + a.w * a.w +
             c.x * c.x + c.y * c.y + c.z * c.z + c.w * c.w;
  float f = sqrtf(sq) / (1.0f + sq);
  a.x *= f; a.y *= f; a.z *= f; a.w *= f;
  c.x *= f; c.y *= f; c.z *= f; c.w *= f;
  *(float4*)up = a;
  *(float4*)(up + 4) = c;
  u16 o[8];
  o[0] = f2h(a.x); o[1] = f2h(a.y); o[2] = f2h(a.z); o[3] = f2h(a.w);
  o[4] = f2h(c.x); o[5] = f2h(c.y); o[6] = f2h(c.z); o[7] = f2h(c.w);
  *(uint4*)(ub + (size_t)idx * 8) = *(uint4*)o;
}

// ---------------- ubT[ri][b] = ub[b][ri] via LDS tile transpose ----------------
__global__ __launch_bounds__(256) void transp_kernel(
    const u16* __restrict__ ub, u16* __restrict__ ubT) {
  __shared__ u16 tl[64][72];
  int ri0 = blockIdx.x * 64, b0 = blockIdx.y * 64;
  int tid = threadIdx.x;
  int br = tid >> 2, cq = tid & 3;
  const u16* ip = ub + (size_t)(b0 + br) * 9216 + ri0 + cq * 16;
  uint4 v0 = *(const uint4*)ip;
  uint4 v1 = *(const uint4*)(ip + 8);
  *(uint4*)&tl[br][cq * 16] = v0;
  *(uint4*)&tl[br][cq * 16 + 8] = v1;
  __syncthreads();
  int rr = tid >> 2, cb = tid & 3;
  u16 o0[8], o1[8];
#pragma unroll
  for (int j = 0; j < 8; ++j) {
    o0[j] = tl[cb * 16 + j][rr];
    o1[j] = tl[cb * 16 + 8 + j][rr];
  }
  u16* opp = ubT + (size_t)(ri0 + rr) * 512 + b0 + cb * 16;
  *(uint4*)opp = *(uint4*)o0;
  *(uint4*)(opp + 8) = *(uint4*)o1;
}

// ---------------- softmax over routes: cT[c][r] = softmax_r(bij[r][c]) ----------------
__global__ __launch_bounds__(256) void softmax_c_kernel(
    const float* __restrict__ bij, float* __restrict__ cT) {
  int c = blockIdx.x;
  int tid = threadIdx.x;
  __shared__ float red[256];
  float mx = -1e30f;
  for (int r = tid; r < 1152; r += 256) mx = fmaxf(mx, bij[r * 10 + c]);
  red[tid] = mx;
  __syncthreads();
  for (int s = 128; s > 0; s >>= 1) {
    if (tid < s) red[tid] = fmaxf(red[tid], red[tid + s]);
    __syncthreads();
  }
  mx = red[0];
  __syncthreads();
  float sum = 0.f;
  for (int r = tid; r < 1152; r += 256) sum += expf(bij[r * 10 + c] - mx);
  red[tid] = sum;
  __syncthreads();
  for (int s = 128; s > 0; s >>= 1) {
    if (tid < s) red[tid] += red[tid + s];
    __syncthreads();
  }
  float inv = 1.0f / red[0];
  for (int r = tid; r < 1152; r += 256)
    cT[c * 1152 + r] = expf(bij[r * 10 + c] - mx) * inv;
}

// ---------------- gemm_s (iters 1-2): s_scaled += fp16(512*cT*W) @ ub^T ----------------
__global__ __launch_bounds__(256) void gemm_s_kernel(
    const float* __restrict__ W, const float* __restrict__ cT,
    const u16* __restrict__ ub, float* __restrict__ s) {
  __shared__ __align__(16) u16 Asl[160 * 72];
  __shared__ __align__(16) u16 Bsl[64 * 72];
  int nb = blockIdx.x & 7, kzi = blockIdx.x >> 3;
  int n0 = nb * 64, k0 = kzi * 256;
  int tid = threadIdx.x;
  int lane = tid & 63, wave = tid >> 6;
  int fr = lane & 15, fg = lane >> 4;

  f32x4 acc[10] = {};
#pragma unroll
  for (int st = 0; st < 4; ++st) {
    int kb = k0 + st * 64;
    __syncthreads();
#pragma unroll
    for (int j = 0; j < 5; ++j) {
      int c5 = tid + j * 256;
      int row = c5 >> 3, qq = c5 & 7;
      int cls = row >> 4, o = row & 15;
      int r = (kb + qq * 8) >> 3;
      const float* wp = W + (size_t)r * 1280 + cls * 128 + o * 8;
      float4 w0 = *(const float4*)wp;
      float4 w1 = *(const float4*)(wp + 4);
      float cs = cT[cls * 1152 + r] * 512.0f;
      u16 ov[8];
      ov[0] = f2h(w0.x * cs); ov[1] = f2h(w0.y * cs);
      ov[2] = f2h(w0.z * cs); ov[3] = f2h(w0.w * cs);
      ov[4] = f2h(w1.x * cs); ov[5] = f2h(w1.y * cs);
      ov[6] = f2h(w1.z * cs); ov[7] = f2h(w1.w * cs);
      *(uint4*)((char*)Asl + row * 144 + qq * 16) = *(uint4*)ov;
    }
#pragma unroll
    for (int j = 0; j < 2; ++j) {
      int c2 = tid + j * 256;
      int row = c2 >> 3, qq = c2 & 7;
      *(uint4*)((char*)Bsl + row * 144 + qq * 16) =
          *(const uint4*)(ub + (size_t)(n0 + row) * 9216 + kb + qq * 8);
    }
    __syncthreads();
#pragma unroll
    for (int s2 = 0; s2 < 2; ++s2) {
      int xg = (s2 * 4 + fg) * 16;
      half8 bf0 = *(const half8*)((char*)Bsl + (wave * 16 + fr) * 144 + xg);
#pragma unroll
      for (int m = 0; m < 10; ++m) {
        half8 af = *(const half8*)((char*)Asl + (m * 16 + fr) * 144 + xg);
        acc[m] = __builtin_amdgcn_mfma_f32_16x16x32_f16(af, bf0, acc[m], 0, 0, 0);
      }
    }
  }
  int bcol = n0 + wave * 16 + fr;
#pragma unroll
  for (int m = 0; m < 10; ++m)
#pragma unroll
    for (int qq = 0; qq < 4; ++qq)
      atomicAdd(s + (m * 16 + fg * 4 + qq) * 512 + bcol, acc[m][qq]);
}

// ---------------- squash_v: v = squash(s/512); vb = fp16(4096*v); re-zeros s ----------------
__global__ __launch_bounds__(256) void squash_v_kernel(
    float* __restrict__ s, u16* __restrict__ vb) {
  int idx = blockIdx.x * 256 + threadIdx.x;  // 5120 = c*512 + b
  int c = idx >> 9, b = idx & 511;
  float vals[16];
  float sq = 0.f;
#pragma unroll
  for (int o = 0; o < 16; ++o) {
    float v = s[(c * 16 + o) * 512 + b] * (1.0f / 512.0f);
    vals[o] = v;
    sq += v * v;
  }
#pragma unroll
  for (int o = 0; o < 16; ++o) s[(c * 16 + o) * 512 + b] = 0.f;
  float f = sqrtf(sq) / (1.0f + sq);
#pragma unroll
  for (int o = 0; o < 16; ++o)
    vb[(c * 16 + o) * 512 + b] = f2h(vals[o] * f * 4096.0f);
}

// ---------------- gemm_gc: G_scaled = vb @ ubT^T then bij += W.G/(512*4096) ----------------
__global__ __launch_bounds__(256) void gemm_gc_kernel(
    const u16* __restrict__ vb, const u16* __restrict__ ubT,
    const float* __restrict__ W, float* __restrict__ bij) {
  __shared__ __align__(16) u16 Agl[160 * 72];
  __shared__ __align__(16) u16 Bgl[128 * 72];
  __shared__ float Gl[160 * 129];
  int nb = blockIdx.x % 72, kzi = blockIdx.x / 72;
  int n0 = nb * 128, k0 = kzi * 128;
  int tid = threadIdx.x;
  int lane = tid & 63, wave = tid >> 6;
  int fr = lane & 15, fg = lane >> 4;
  f32x4 acc[10][2] = {};
#pragma unroll
  for (int st = 0; st < 2; ++st) {
    int kb = k0 + st * 64;
    __syncthreads();
#pragma unroll
    for (int j = 0; j < 5; ++j) {
      int c5 = tid + j * 256;
      int row = c5 >> 3, qq = c5 & 7;
      *(uint4*)((char*)Agl + row * 144 + qq * 16) =
          *(const uint4*)(vb + (size_t)row * 512 + kb + qq * 8);
    }
#pragma unroll
    for (int j = 0; j < 4; ++j) {
      int c4 = tid + j * 256;
      int row = c4 >> 3, qq = c4 & 7;
      *(uint4*)((char*)Bgl + row * 144 + qq * 16) =
          *(const uint4*)(ubT + (size_t)(n0 + row) * 512 + kb + qq * 8);
    }
    __syncthreads();
#pragma unroll
    for (int s2 = 0; s2 < 2; ++s2) {
      int xg = (s2 * 4 + fg) * 16;
      half8 bfv[2];
#pragma unroll
      for (int nn = 0; nn < 2; ++nn)
        bfv[nn] = *(const half8*)((char*)Bgl + (wave * 32 + nn * 16 + fr) * 144 + xg);
#pragma unroll
      for (int m = 0; m < 10; ++m) {
        half8 af = *(const half8*)((char*)Agl + (m * 16 + fr) * 144 + xg);
#pragma unroll
        for (int nn = 0; nn < 2; ++nn)
          acc[m][nn] = __builtin_amdgcn_mfma_f32_16x16x32_f16(af, bfv[nn],
                                                             acc[m][nn], 0, 0, 0);
      }
    }
  }
#pragma unroll
  for (int m = 0; m < 10; ++m)
#pragma unroll
    for (int nn = 0; nn < 2; ++nn) {
      int col = wave * 32 + nn * 16 + fr;
#pragma unroll
      for (int qq = 0; qq < 4; ++qq)
        Gl[(m * 16 + fg * 4 + qq) * 129 + col] = acc[m][nn][qq];
    }
  __syncthreads();
  if (tid < 160) {
    int rl = tid / 10, c = tid - rl * 10;
    int r = (n0 >> 3) + rl;
    const float* wp = W + (size_t)r * 1280 + c * 128;
    float a = 0.f;
#pragma unroll 4
    for (int o = 0; o < 16; ++o) {
      const float* gp = &Gl[(c * 16 + o) * 129 + rl * 8];
#pragma unroll
      for (int i = 0; i < 8; ++i) a = fmaf(wp[o * 8 + i], gp[i], a);
    }
    atomicAdd(&bij[r * 10 + c], a * (1.0f / (512.0f * 4096.0f)));
  }
}

// ---------------- route_final: out = squash(sum_r c_r * (W.u_sq)) in FP32 ----------------
// EXACT r10 body (global W reads) — the reproduced 6.1e-5 basin.
__global__ __launch_bounds__(256) void route_final_kernel(
    const float* __restrict__ cT, const float* __restrict__ u,
    const float* __restrict__ W, float* __restrict__ outp) {
  int c = blockIdx.y, b0 = blockIdx.x * 16;
  int tid = threadIdx.x, lb = tid >> 4, o = tid & 15;
  __shared__ float us[16][32][8];
  __shared__ float cs[32];
  float acc = 0.f;
  for (int r0 = 0; r0 < 1152; r0 += 32) {
    __syncthreads();
#pragma unroll
    for (int j = 0; j < 4; ++j) {
      int i4 = tid + j * 256;            // 0..1023 float4s
      int bb = i4 >> 6, rem = i4 & 63;
      int rr = rem >> 1, hf = rem & 1;
      *(float4*)&us[bb][rr][hf * 4] =
          *(const float4*)&u[(size_t)(b0 + bb) * 9216 + (r0 + rr) * 8 + hf * 4];
    }
    if (tid < 32) cs[tid] = cT[c * 1152 + r0 + tid];
    __syncthreads();
#pragma unroll 4
    for (int rr = 0; rr < 32; ++rr) {
      const float* wp = W + ((size_t)(r0 + rr) * 10 + c) * 128 + o * 8;
      float4 w0 = *(const float4*)wp;
      float4 w1v = *(const float4*)(wp + 4);
      float4 ua = *(const float4*)&us[lb][rr][0];
      float4 ub4 = *(const float4*)&us[lb][rr][4];
      float d = w0.x * ua.x + w0.y * ua.y + w0.z * ua.z + w0.w * ua.w +
                w1v.x * ub4.x + w1v.y * ub4.y + w1v.z * ub4.z + w1v.w * ub4.w;
      acc = fmaf(cs[rr], d, acc);
    }
  }
  float sq = acc * acc;
  sq += __shfl_xor(sq, 1, 64);
  sq += __shfl_xor(sq, 2, 64);
  sq += __shfl_xor(sq, 4, 64);
  sq += __shfl_xor(sq, 8, 64);
  float f = sqrtf(sq) / (1.0f + sq);
  outp[((size_t)(b0 + lb) * 10 + c) * 16 + o] = acc * f;
}

extern "C" void kernel_launch(void* const* d_in, const int* in_sizes, int n_in,
                              void* d_out, int out_size, void* d_ws, size_t ws_size,
                              hipStream_t stream) {
  const float* x  = (const float*)d_in[0];
  const float* w1 = (const float*)d_in[1];
  const float* b1 = (const float*)d_in[2];
  const float* w2 = (const float*)d_in[3];
  const float* b2 = (const float*)d_in[4];
  const float* W  = (const float*)d_in[5];
  char* ws = (char*)d_ws;
  u16*   hT  = (u16*)ws;
  u16*   A2  = (u16*)(ws + 104857600);
  float* u   = (float*)(ws + 115474432);
  float* bij = (float*)(ws + 134348800);
  float* cT  = (float*)(ws + 134394880);
  float* s   = (float*)(ws + 134440960);
  u16*   ub  = (u16*)ws;                 // aliases dead hT
  u16*   ubT = (u16*)(ws + 9437184);
  u16*   vb  = (u16*)(ws + 21823488);
  float* out = (float*)d_out;

  hipMemsetAsync(bij, 0, 46080, stream);
  hipMemsetAsync(s, 0, 327680, stream);
  prologue_kernel<<<5888, 256, 0, stream>>>(x, w1, b1, w2, b2, hT, A2, u);
  conv2_kernel<<<216, 1024, 0, stream>>>(hT, A2, u);
  squash_kernel<<<2304, 256, 0, stream>>>(u, ub);
  transp_kernel<<<dim3(144, 8), 256, 0, stream>>>(ub, ubT);
  for (int it = 0; it < 3; ++it) {
    softmax_c_kernel<<<10, 256, 0, stream>>>(bij, cT);
    if (it < 2) {
      gemm_s_kernel<<<288, 256, 0, stream>>>(W, cT, ub, s);
      squash_v_kernel<<<20, 256, 0, stream>>>(s, vb);
      gemm_gc_kernel<<<288, 256, 0, stream>>>(vb, ubT, W, bij);
    } else {
      route_final_kernel<<<dim3(32, 10), 256, 0, stream>>>(cT, u, W, out);
    }
  }
}

// Round 19
// 612.246 us; speedup vs baseline: 1.0067x; 1.0067x over previous
//
#include <hip/hip_runtime.h>
#include <stdint.h>

// CapsuleNet forward on MI355X — round 19 (small-kernel consolidation).
// 1) gemm_s split-K 36->72 (grid 576), gemm_gc split-K 4->8 (grid 576):
//    halves per-block serial span of the latency-bound routing GEMMs.
// 2) squash+transp fused (u/ub/ubT bitwise identical to r18's pair).
// 3) memsets folded into prologue (2 fewer dispatches).
// conv2 (r17 16-wave, 239us) and route_final (r10 basin body) frozen.
//
// ws layout (total ~134.8 MB):
//   hT  fp16 [512][20][20][256]   @0           104,857,600
//   A2  fp16 [256][20736]         @104,857,600  10,616,832
//   u   f32  [512][9216]          @115,474,432  18,874,368  (squashed in place)
//   bij f32  [1152][10]           @134,348,800      46,080
//   cT  f32  [10][1152]           @134,394,880      46,080
//   s   f32  [160][512]           @134,440,960     327,680
//  aliased over dead hT after conv2:
//   ub  fp16 [512][9216]          @0             9,437,184
//   ubT fp16 [9216][512]          @9,437,184     9,437,184
//   vb  fp16 [160][512]           @21,823,488      163,840

typedef unsigned short u16;
typedef unsigned int u32;
typedef _Float16 half8 __attribute__((ext_vector_type(8)));
typedef float f32x4 __attribute__((ext_vector_type(4)));

__device__ __forceinline__ u16 f2h(float f) {
  union { _Float16 h; u16 u; } cv;
  cv.h = (_Float16)f;
  return cv.u;
}

__device__ __forceinline__ void gload_lds16(const void* g, void* l) {
  __builtin_amdgcn_global_load_lds(
      (const __attribute__((address_space(1))) void*)g,
      (__attribute__((address_space(3))) void*)l, 16, 0, 0);
}

// ---------------- prologue: conv1 | prep_w2 | init_u | zero bij+s ----------------
__global__ __launch_bounds__(256) void prologue_kernel(
    const float* __restrict__ x, const float* __restrict__ w1,
    const float* __restrict__ b1, const float* __restrict__ w2,
    const float* __restrict__ b2, u16* __restrict__ hT,
    u16* __restrict__ A2, float* __restrict__ u,
    float* __restrict__ bij, float* __restrict__ s) {
  __shared__ __align__(16) char smraw[81 * 264 * 2];  // union: xs / tl
  int bid = blockIdx.x;
  int tid = threadIdx.x;
  if (bid < 1024) {
    // ---- conv1: lane=co, 10 output rows per block, x rows in LDS ----
    float* xs = (float*)smraw;  // 18 input rows = 504 floats
    int b = bid >> 1, half = bid & 1;
    int co = tid;
    const float* xbase = x + (size_t)b * 784 + half * 280;
    for (int i = co; i < 504; i += 256) xs[i] = xbase[i];
    float w[81];
    const float* wp = w1 + co * 81;
#pragma unroll
    for (int k = 0; k < 81; ++k) w[k] = wp[k];
    float bias = b1[co];
    __syncthreads();
    u16* hb = hT + (size_t)b * 102400 + co;
    for (int yp = 0; yp < 5; ++yp) {
      int y0l = yp * 2;
      int y0g = half * 10 + y0l;
      for (int g = 0; g < 5; ++g) {
        int xo = g * 4;
        float a0[4], a1[4];
#pragma unroll
        for (int j = 0; j < 4; ++j) { a0[j] = bias; a1[j] = bias; }
#pragma unroll
        for (int ky2 = 0; ky2 < 10; ++ky2) {
          const float* row = &xs[(y0l + ky2) * 28 + xo];
          float4 r0 = *(const float4*)row;
          float4 r1 = *(const float4*)(row + 4);
          float4 r2 = *(const float4*)(row + 8);
          float xr[12] = {r0.x, r0.y, r0.z, r0.w, r1.x, r1.y, r1.z, r1.w,
                          r2.x, r2.y, r2.z, r2.w};
          if (ky2 < 9) {
#pragma unroll
            for (int kx = 0; kx < 9; ++kx) {
              float wv = w[ky2 * 9 + kx];
              a0[0] = fmaf(wv, xr[kx], a0[0]);
              a0[1] = fmaf(wv, xr[kx + 1], a0[1]);
              a0[2] = fmaf(wv, xr[kx + 2], a0[2]);
              a0[3] = fmaf(wv, xr[kx + 3], a0[3]);
            }
          }
          if (ky2 >= 1) {
#pragma unroll
            for (int kx = 0; kx < 9; ++kx) {
              float wv = w[(ky2 - 1) * 9 + kx];
              a1[0] = fmaf(wv, xr[kx], a1[0]);
              a1[1] = fmaf(wv, xr[kx + 1], a1[1]);
              a1[2] = fmaf(wv, xr[kx + 2], a1[2]);
              a1[3] = fmaf(wv, xr[kx + 3], a1[3]);
            }
          }
        }
#pragma unroll
        for (int j = 0; j < 4; ++j) {
          hb[(y0g * 20 + xo + j) * 256] = f2h(fmaxf(a0[j], 0.f));
          hb[((y0g + 1) * 20 + xo + j) * 256] = f2h(fmaxf(a1[j], 0.f));
        }
      }
    }
  } else if (bid < 1280) {
    // ---- prep_w2 ----
    u16* tl = (u16*)smraw;  // pitch 264 u16
    int co = bid - 1024;
    const float* wp = w2 + (size_t)co * 20736;
#pragma unroll
    for (int k = 0; k < 81; ++k) {
      int li = k * 256 + tid;  // li = ci*81 + t
      int ci = li / 81, t = li - ci * 81;
      tl[t * 264 + ci] = f2h(wp[li]);
    }
    __syncthreads();
    u16* op = A2 + (size_t)co * 20736;
    for (int oc = tid; oc < 2592; oc += 256) {
      int k0 = oc * 8;
      int t = k0 >> 8, ci0 = k0 & 255;
      *(uint4*)(op + k0) = *(const uint4*)&tl[t * 264 + ci0];
    }
  } else if (bid < 5888) {
    // ---- init_u ----
    int i = (bid - 1280) * 256 + tid;
    int b = i / 2304, j0 = (i - b * 2304) * 4;
    float4 v;
    v.x = b2[j0 / 36]; v.y = b2[(j0 + 1) / 36];
    v.z = b2[(j0 + 2) / 36]; v.w = b2[(j0 + 3) / 36];
    *(float4*)(u + (size_t)b * 9216 + j0) = v;
  } else {
    // ---- zero bij (2880 f4) then s (20480 f4) ----
    int i4 = (bid - 5888) * 256 + tid;
    if (i4 < 23360) {
      float4 z = make_float4(0.f, 0.f, 0.f, 0.f);
      if (i4 < 2880) *(float4*)(bij + i4 * 4) = z;
      else *(float4*)(s + (i4 - 2880) * 4) = z;
    }
  }
}

// ---------------- conv2 implicit GEMM: 256x256, BK=64, 16 waves of 64x64 (r17) ----------------
__global__ __launch_bounds__(1024, 4) void conv2_kernel(
    const u16* __restrict__ hT, const u16* __restrict__ A2,
    float* __restrict__ u) {
  __shared__ __align__(16) u16 lds_[65536];  // 131072 B = 2 bufs x (A 32KB | B 32KB)
  char* const ldsc = (char*)lds_;
  const int bx = blockIdx.x;
  const int nbk = bx % 72, kz = bx / 72;
  const int n0 = nbk * 256;
  const int tid = threadIdx.x;
  const int lane = tid & 63, w = tid >> 6;  // w 0..15
  const int wr = w >> 2, wc = w & 3;        // 4x4 wave grid
  const int fr = lane & 15, fg = lane >> 4;
  const int w1024 = w * 1024;

  const int rA = tid >> 3;                  // 0..127
  const int qs = (tid & 7) ^ (rA & 7);      // source pre-swizzle (rule 21)
  const int Aoff0 = rA * 20736 + qs * 8;
  const int Aoff1 = (128 + rA) * 20736 + qs * 8;
  int Bb0, Bb1;
  {
    int n = n0 + rA;
    int b = n / 36, sp = n - b * 36, oh = sp / 6, ow = sp - oh * 6;
    Bb0 = (b * 400 + oh * 40 + ow * 2) * 256 + qs * 8;
    n = n0 + 128 + rA;
    b = n / 36; sp = n - b * 36; oh = sp / 6; ow = sp - oh * 6;
    Bb1 = (b * 400 + oh * 40 + ow * 2) * 256 + qs * 8;
  }

  const int kx0 = (fg ^ (fr & 7)) << 4;
  const int kx1 = ((4 + fg) ^ (fr & 7)) << 4;
  const int arow = wr * 64 + fr;  // + mr*16
  const int brow = wc * 64 + fr;  // + nr*16

  f32x4 acc[4][4] = {};
  half8 areg[4], breg[4];

#define STAGE4(E, GT) do {                                                   \
    int tap_ = (GT) >> 2;                                                    \
    int kh_ = tap_ / 9, kw_ = tap_ - kh_ * 9;                                \
    int bo_ = (kh_ * 20 + kw_) * 256 + ((GT) & 3) * 64;                      \
    char* base_ = ldsc + (E) * 65536;                                        \
    gload_lds16(A2 + Aoff0 + (GT) * 64, base_ + w1024);                      \
    gload_lds16(A2 + Aoff1 + (GT) * 64, base_ + 16384 + w1024);              \
    gload_lds16(hT + Bb0 + bo_, base_ + 32768 + w1024);                      \
    gload_lds16(hT + Bb1 + bo_, base_ + 49152 + w1024);                      \
  } while (0)
#define RD8(D, KX) do { _Pragma("unroll")                                    \
    for (int mr = 0; mr < 4; ++mr)                                           \
      areg[mr] = *(const half8*)(ldsc + (D) * 65536 +                        \
                                 (arow + mr * 16) * 128 + (KX));             \
    _Pragma("unroll")                                                        \
    for (int nr = 0; nr < 4; ++nr)                                           \
      breg[nr] = *(const half8*)(ldsc + (D) * 65536 + 32768 +                \
                                 (brow + nr * 16) * 128 + (KX));             \
  } while (0)
#define MM16() do {                                                          \
    __builtin_amdgcn_s_setprio(1);                                           \
    _Pragma("unroll") for (int mr = 0; mr < 4; ++mr)                         \
    _Pragma("unroll") for (int nr = 0; nr < 4; ++nr)                         \
      acc[mr][nr] = __builtin_amdgcn_mfma_f32_16x16x32_f16(                  \
          areg[mr], breg[nr], acc[mr][nr], 0, 0, 0);                         \
    __builtin_amdgcn_s_setprio(0);                                           \
  } while (0)
#define LGKM() do {                                                          \
    asm volatile("s_waitcnt lgkmcnt(0)" ::: "memory");                       \
    __builtin_amdgcn_sched_barrier(0);                                       \
  } while (0)
#define VM_BAR0() do {                                                       \
    asm volatile("s_waitcnt vmcnt(0)" ::: "memory");                         \
    __builtin_amdgcn_s_barrier();                                            \
    asm volatile("" ::: "memory");                                           \
  } while (0)
#define TILE_STD(T, D, E) do {                                               \
    RD8(D, kx0);                                                             \
    STAGE4(E, kz * 108 + (T) + 1);                                           \
    LGKM(); MM16();                                                          \
    RD8(D, kx1); LGKM(); MM16();                                             \
    VM_BAR0();                                                               \
  } while (0)
#define TILE_LAST(D) do {                                                    \
    RD8(D, kx0); LGKM(); MM16();                                             \
    RD8(D, kx1); LGKM(); MM16();                                             \
  } while (0)

  STAGE4(0, kz * 108);
  asm volatile("s_waitcnt vmcnt(0)" ::: "memory");
  __builtin_amdgcn_s_barrier();
  asm volatile("" ::: "memory");

  for (int tt = 0; tt < 53; ++tt) {
    TILE_STD(2 * tt, 0, 1);
    TILE_STD(2 * tt + 1, 1, 0);
  }
  TILE_STD(106, 0, 1);
  TILE_LAST(1);

#pragma unroll
  for (int nf = 0; nf < 4; ++nf) {
    int cn = n0 + wc * 64 + nf * 16 + fr;
    int ob = cn / 36;
    int os = cn - ob * 36;
    float* op = u + (size_t)ob * 9216 + os;
#pragma unroll
    for (int mf = 0; mf < 4; ++mf) {
      int row0 = wr * 64 + mf * 16 + fg * 4;
#pragma unroll
      for (int qq = 0; qq < 4; ++qq)
        atomicAdd(op + (row0 + qq) * 36, acc[mf][nf][qq]);
    }
  }
#undef STAGE4
#undef RD8
#undef MM16
#undef LGKM
#undef VM_BAR0
#undef TILE_STD
#undef TILE_LAST
}

// ---------------- squashT: u := squash(u) in place + ub fp16 + ubT (fused transp) ----------------
// grid (144 ri-tiles, 8 b-tiles). Per-capsule fp32 math identical to r18's
// squash -> u/ub bitwise identical; ubT written via LDS tile (values identical).
__global__ __launch_bounds__(256) void squashT_kernel(
    float* __restrict__ u, u16* __restrict__ ub, u16* __restrict__ ubT) {
  __shared__ u16 tl[64][72];
  int ri0 = blockIdx.x * 64, b0 = blockIdx.y * 64;
  int r0 = ri0 >> 3;
  int tid = threadIdx.x;
#pragma unroll
  for (int hcap = 0; hcap < 2; ++hcap) {
    int cap = hcap * 256 + tid;       // 0..511 = bb*8 + rr
    int bb = cap >> 3, rr = cap & 7;
    float* up = u + (size_t)(b0 + bb) * 9216 + (r0 + rr) * 8;
    float4 a = *(const float4*)up;
    float4 c = *(const float4*)(up + 4);
    float sq = a.x * a.x + a.y * a.y + a.z * a.z + a.w * a.w +
               c.x * c.x + c.y * c.y + c.z * c.z + c.w * c.w;
    float f = sqrtf(sq) / (1.0f + sq);
    a.x *= f; a.y *= f; a.z *= f; a.w *= f;
    c.x *= f; c.y *= f; c.z *= f; c.w *= f;
    *(float4*)up = a;
    *(float4*)(up + 4) = c;
    u16 o[8];
    o[0] = f2h(a.x); o[1] = f2h(a.y); o[2] = f2h(a.z); o[3] = f2h(a.w);
    o[4] = f2h(c.x); o[5] = f2h(c.y); o[6] = f2h(c.z); o[7] = f2h(c.w);
    *(uint4*)(ub + (size_t)(b0 + bb) * 9216 + (r0 + rr) * 8) = *(uint4*)o;
    *(uint4*)&tl[bb][rr * 8] = *(uint4*)o;
  }
  __syncthreads();
  int rr2 = tid >> 2, cb = tid & 3;
  u16 o0[8], o1[8];
#pragma unroll
  for (int j = 0; j < 8; ++j) {
    o0[j] = tl[cb * 16 + j][rr2];
    o1[j] = tl[cb * 16 + 8 + j][rr2];
  }
  u16* opp = ubT + (size_t)(ri0 + rr2) * 512 + b0 + cb * 16;
  *(uint4*)opp = *(uint4*)o0;
  *(uint4*)(opp + 8) = *(uint4*)o1;
}

// ---------------- softmax over routes: cT[c][r] = softmax_r(bij[r][c]) ----------------
__global__ __launch_bounds__(256) void softmax_c_kernel(
    const float* __restrict__ bij, float* __restrict__ cT) {
  int c = blockIdx.x;
  int tid = threadIdx.x;
  __shared__ float red[256];
  float mx = -1e30f;
  for (int r = tid; r < 1152; r += 256) mx = fmaxf(mx, bij[r * 10 + c]);
  red[tid] = mx;
  __syncthreads();
  for (int s = 128; s > 0; s >>= 1) {
    if (tid < s) red[tid] = fmaxf(red[tid], red[tid + s]);
    __syncthreads();
  }
  mx = red[0];
  __syncthreads();
  float sum = 0.f;
  for (int r = tid; r < 1152; r += 256) sum += expf(bij[r * 10 + c] - mx);
  red[tid] = sum;
  __syncthreads();
  for (int s = 128; s > 0; s >>= 1) {
    if (tid < s) red[tid] += red[tid + s];
    __syncthreads();
  }
  float inv = 1.0f / red[0];
  for (int r = tid; r < 1152; r += 256)
    cT[c * 1152 + r] = expf(bij[r * 10 + c] - mx) * inv;
}

// ---------------- gemm_s (iters 1-2): s_scaled += fp16(512*cT*W) @ ub^T ----------------
// split-K 72 (K=128/block, 2 BK-64 steps), grid 576 = 8 nb * 72 kz.
__global__ __launch_bounds__(256) void gemm_s_kernel(
    const float* __restrict__ W, const float* __restrict__ cT,
    const u16* __restrict__ ub, float* __restrict__ s) {
  __shared__ __align__(16) u16 Asl[160 * 72];
  __shared__ __align__(16) u16 Bsl[64 * 72];
  int nb = blockIdx.x & 7, kzi = blockIdx.x >> 3;
  int n0 = nb * 64, k0 = kzi * 128;
  int tid = threadIdx.x;
  int lane = tid & 63, wave = tid >> 6;
  int fr = lane & 15, fg = lane >> 4;

  f32x4 acc[10] = {};
#pragma unroll
  for (int st = 0; st < 2; ++st) {
    int kb = k0 + st * 64;
    __syncthreads();
#pragma unroll
    for (int j = 0; j < 5; ++j) {
      int c5 = tid + j * 256;
      int row = c5 >> 3, qq = c5 & 7;
      int cls = row >> 4, o = row & 15;
      int r = (kb + qq * 8) >> 3;
      const float* wp = W + (size_t)r * 1280 + cls * 128 + o * 8;
      float4 w0 = *(const float4*)wp;
      float4 w1 = *(const float4*)(wp + 4);
      float cs = cT[cls * 1152 + r] * 512.0f;
      u16 ov[8];
      ov[0] = f2h(w0.x * cs); ov[1] = f2h(w0.y * cs);
      ov[2] = f2h(w0.z * cs); ov[3] = f2h(w0.w * cs);
      ov[4] = f2h(w1.x * cs); ov[5] = f2h(w1.y * cs);
      ov[6] = f2h(w1.z * cs); ov[7] = f2h(w1.w * cs);
      *(uint4*)((char*)Asl + row * 144 + qq * 16) = *(uint4*)ov;
    }
#pragma unroll
    for (int j = 0; j < 2; ++j) {
      int c2 = tid + j * 256;
      int row = c2 >> 3, qq = c2 & 7;
      *(uint4*)((char*)Bsl + row * 144 + qq * 16) =
          *(const uint4*)(ub + (size_t)(n0 + row) * 9216 + kb + qq * 8);
    }
    __syncthreads();
#pragma unroll
    for (int s2 = 0; s2 < 2; ++s2) {
      int xg = (s2 * 4 + fg) * 16;
      half8 bf0 = *(const half8*)((char*)Bsl + (wave * 16 + fr) * 144 + xg);
#pragma unroll
      for (int m = 0; m < 10; ++m) {
        half8 af = *(const half8*)((char*)Asl + (m * 16 + fr) * 144 + xg);
        acc[m] = __builtin_amdgcn_mfma_f32_16x16x32_f16(af, bf0, acc[m], 0, 0, 0);
      }
    }
  }
  int bcol = n0 + wave * 16 + fr;
#pragma unroll
  for (int m = 0; m < 10; ++m)
#pragma unroll
    for (int qq = 0; qq < 4; ++qq)
      atomicAdd(s + (m * 16 + fg * 4 + qq) * 512 + bcol, acc[m][qq]);
}

// ---------------- squash_v: v = squash(s/512); vb = fp16(4096*v); re-zeros s ----------------
__global__ __launch_bounds__(256) void squash_v_kernel(
    float* __restrict__ s, u16* __restrict__ vb) {
  int idx = blockIdx.x * 256 + threadIdx.x;  // 5120 = c*512 + b
  int c = idx >> 9, b = idx & 511;
  float vals[16];
  float sq = 0.f;
#pragma unroll
  for (int o = 0; o < 16; ++o) {
    float v = s[(c * 16 + o) * 512 + b] * (1.0f / 512.0f);
    vals[o] = v;
    sq += v * v;
  }
#pragma unroll
  for (int o = 0; o < 16; ++o) s[(c * 16 + o) * 512 + b] = 0.f;
  float f = sqrtf(sq) / (1.0f + sq);
#pragma unroll
  for (int o = 0; o < 16; ++o)
    vb[(c * 16 + o) * 512 + b] = f2h(vals[o] * f * 4096.0f);
}

// ---------------- gemm_gc: G_scaled = vb @ ubT^T then bij += W.G/(512*4096) ----------------
// split-K 8 (K=64/block, 1 step), grid 576 = 72 nb * 8 kz.
__global__ __launch_bounds__(256) void gemm_gc_kernel(
    const u16* __restrict__ vb, const u16* __restrict__ ubT,
    const float* __restrict__ W, float* __restrict__ bij) {
  __shared__ __align__(16) u16 Agl[160 * 72];
  __shared__ __align__(16) u16 Bgl[128 * 72];
  __shared__ float Gl[160 * 129];
  int nb = blockIdx.x % 72, kzi = blockIdx.x / 72;
  int n0 = nb * 128, kb = kzi * 64;
  int tid = threadIdx.x;
  int lane = tid & 63, wave = tid >> 6;
  int fr = lane & 15, fg = lane >> 4;
  f32x4 acc[10][2] = {};
  {
#pragma unroll
    for (int j = 0; j < 5; ++j) {
      int c5 = tid + j * 256;
      int row = c5 >> 3, qq = c5 & 7;
      *(uint4*)((char*)Agl + row * 144 + qq * 16) =
          *(const uint4*)(vb + (size_t)row * 512 + kb + qq * 8);
    }
#pragma unroll
    for (int j = 0; j < 4; ++j) {
      int c4 = tid + j * 256;
      int row = c4 >> 3, qq = c4 & 7;
      *(uint4*)((char*)Bgl + row * 144 + qq * 16) =
          *(const uint4*)(ubT + (size_t)(n0 + row) * 512 + kb + qq * 8);
    }
    __syncthreads();
#pragma unroll
    for (int s2 = 0; s2 < 2; ++s2) {
      int xg = (s2 * 4 + fg) * 16;
      half8 bfv[2];
#pragma unroll
      for (int nn = 0; nn < 2; ++nn)
        bfv[nn] = *(const half8*)((char*)Bgl + (wave * 32 + nn * 16 + fr) * 144 + xg);
#pragma unroll
      for (int m = 0; m < 10; ++m) {
        half8 af = *(const half8*)((char*)Agl + (m * 16 + fr) * 144 + xg);
#pragma unroll
        for (int nn = 0; nn < 2; ++nn)
          acc[m][nn] = __builtin_amdgcn_mfma_f32_16x16x32_f16(af, bfv[nn],
                                                             acc[m][nn], 0, 0, 0);
      }
    }
  }
#pragma unroll
  for (int m = 0; m < 10; ++m)
#pragma unroll
    for (int nn = 0; nn < 2; ++nn) {
      int col = wave * 32 + nn * 16 + fr;
#pragma unroll
      for (int qq = 0; qq < 4; ++qq)
        Gl[(m * 16 + fg * 4 + qq) * 129 + col] = acc[m][nn][qq];
    }
  __syncthreads();
  if (tid < 160) {
    int rl = tid / 10, c = tid - rl * 10;
    int r = (n0 >> 3) + rl;
    const float* wp = W + (size_t)r * 1280 + c * 128;
    float a = 0.f;
#pragma unroll 4
    for (int o = 0; o < 16; ++o) {
      const float* gp = &Gl[(c * 16 + o) * 129 + rl * 8];
#pragma unroll
      for (int i = 0; i < 8; ++i) a = fmaf(wp[o * 8 + i], gp[i], a);
    }
    atomicAdd(&bij[r * 10 + c], a * (1.0f / (512.0f * 4096.0f)));
  }
}

// ---------------- route_final: out = squash(sum_r c_r * (W.u_sq)) in FP32 ----------------
// EXACT r10 body (global W reads) — the reproduced 6.1e-5 basin.
__global__ __launch_bounds__(256) void route_final_kernel(
    const float* __restrict__ cT, const float* __restrict__ u,
    const float* __restrict__ W, float* __restrict__ outp) {
  int c = blockIdx.y, b0 = blockIdx.x * 16;
  int tid = threadIdx.x, lb = tid >> 4, o = tid & 15;
  __shared__ float us[16][32][8];
  __shared__ float cs[32];
  float acc = 0.f;
  for (int r0 = 0; r0 < 1152; r0 += 32) {
    __syncthreads();
#pragma unroll
    for (int j = 0; j < 4; ++j) {
      int i4 = tid + j * 256;            // 0..1023 float4s
      int bb = i4 >> 6, rem = i4 & 63;
      int rr = rem >> 1, hf = rem & 1;
      *(float4*)&us[bb][rr][hf * 4] =
          *(const float4*)&u[(size_t)(b0 + bb) * 9216 + (r0 + rr) * 8 + hf * 4];
    }
    if (tid < 32) cs[tid] = cT[c * 1152 + r0 + tid];
    __syncthreads();
#pragma unroll 4
    for (int rr = 0; rr < 32; ++rr) {
      const float* wp = W + ((size_t)(r0 + rr) * 10 + c) * 128 + o * 8;
      float4 w0 = *(const float4*)wp;
      float4 w1v = *(const float4*)(wp + 4);
      float4 ua = *(const float4*)&us[lb][rr][0];
      float4 ub4 = *(const float4*)&us[lb][rr][4];
      float d = w0.x * ua.x + w0.y * ua.y + w0.z * ua.z + w0.w * ua.w +
                w1v.x * ub4.x + w1v.y * ub4.y + w1v.z * ub4.z + w1v.w * ub4.w;
      acc = fmaf(cs[rr], d, acc);
    }
  }
  float sq = acc * acc;
  sq += __shfl_xor(sq, 1, 64);
  sq += __shfl_xor(sq, 2, 64);
  sq += __shfl_xor(sq, 4, 64);
  sq += __shfl_xor(sq, 8, 64);
  float f = sqrtf(sq) / (1.0f + sq);
  outp[((size_t)(b0 + lb) * 10 + c) * 16 + o] = acc * f;
}

extern "C" void kernel_launch(void* const* d_in, const int* in_sizes, int n_in,
                              void* d_out, int out_size, void* d_ws, size_t ws_size,
                              hipStream_t stream) {
  const float* x  = (const float*)d_in[0];
  const float* w1 = (const float*)d_in[1];
  const float* b1 = (const float*)d_in[2];
  const float* w2 = (const float*)d_in[3];
  const float* b2 = (const float*)d_in[4];
  const float* W  = (const float*)d_in[5];
  char* ws = (char*)d_ws;
  u16*   hT  = (u16*)ws;
  u16*   A2  = (u16*)(ws + 104857600);
  float* u   = (float*)(ws + 115474432);
  float* bij = (float*)(ws + 134348800);
  float* cT  = (float*)(ws + 134394880);
  float* s   = (float*)(ws + 134440960);
  u16*   ub  = (u16*)ws;                 // aliases dead hT
  u16*   ubT = (u16*)(ws + 9437184);
  u16*   vb  = (u16*)(ws + 21823488);
  float* out = (float*)d_out;

  prologue_kernel<<<5980, 256, 0, stream>>>(x, w1, b1, w2, b2, hT, A2, u, bij, s);
  conv2_kernel<<<216, 1024, 0, stream>>>(hT, A2, u);
  squashT_kernel<<<dim3(144, 8), 256, 0, stream>>>(u, ub, ubT);
  for (int it = 0; it < 3; ++it) {
    softmax_c_kernel<<<10, 256, 0, stream>>>(bij, cT);
    if (it < 2) {
      gemm_s_kernel<<<576, 256, 0, stream>>>(W, cT, ub, s);
      squash_v_kernel<<<20, 256, 0, stream>>>(s, vb);
      gemm_gc_kernel<<<576, 256, 0, stream>>>(vb, ubT, W, bij);
    } else {
      route_final_kernel<<<dim3(32, 10), 256, 0, stream>>>(cT, u, W, out);
    }
  }
}